// Round 12
// baseline (329.073 us; speedup 1.0000x reference)
//
#include <hip/hip_runtime.h>
#include <hip/hip_fp16.h>

// Problem geometry (fixed by the reference)
#define NROWS   32768      // out_features N
#define KTOT    8192       // in_features K
#define KP      1024       // packed bytes per row (each stored as one int32 on device)
#define GROUPS  64         // scale groups per row (K/128)

// Split-K design (R7, proven): 512-weight slices + sign-symmetric 128-entry LUT
#define SLICE_W 512        // weights per K-slice
#define SLICE_I 64         // int32 elements per slice per row (256 B granule)
#define NSLICES (KTOT / SLICE_W)        // 16
#define BLK     512        // 8 waves
#define ROWS_PER_BLK 512
#define RCHUNKS (NROWS / ROWS_PER_BLK)  // 64 -> grid 1024 = 4 blocks/CU
#define LUTW    132        // 128 entries + 4 pad

typedef int intv4 __attribute__((ext_vector_type(4)));

// ---------------------------------------------------------------------------
// Pass 1 + ticket-fused scale pass.
// Main phase (R7 verbatim + nt LOADS only): one block = one K-slice
// (4 groups) x 512 rows -> UNSCALED fp16 partials pTh[g*NROWS + r] via
// NORMAL stores (nt stores broke release ordering in R11 -> stale reads).
// Tail phase: the 16th block to finish a chunk (device-scope ticket:
// __threadfence + atomicAdd, per G16) runs the proven R4 scale-pass for
// that chunk's 512 rows; scales staged into LDS overlaid on the dead LUT.
// ---------------------------------------------------------------------------
__global__ __launch_bounds__(BLK, 8)
void bitlin_fused(const float* __restrict__ x,
                  const int* __restrict__ packed,
                  const float* __restrict__ scales,
                  __half* __restrict__ pTh,
                  int* __restrict__ cnt,
                  float* __restrict__ out)
{
    __shared__ float lut[SLICE_W / 8][LUTW];   // 33.8 KB; overlaid in tail
    __shared__ int ticket;

    const int s     = blockIdx.x & (NSLICES - 1);  // K-slice id (0..15)
    const int chunk = blockIdx.x >> 4;             // row-chunk id (0..63)
    const int tid   = threadIdx.x;

    // ---- Build half-LUT (R7 verbatim): thread owns (pos = tid>>3, h = tid&7),
    // Gray-walks the low nibble. idx bits 0..3 -> x0..x3, 4..6 -> x4..x6;
    // bit7 == 0 => x7 coefficient always -1.
    {
        const int pos = tid >> 3;          // 0..63
        const int h   = tid & 7;
        float xs[8];
#pragma unroll
        for (int i = 0; i < 8; ++i) xs[i] = x[s * SLICE_W + pos * 8 + i];
        float e = -xs[0] - xs[1] - xs[2] - xs[3]
                + ((h & 1) ? xs[4] : -xs[4])
                + ((h & 2) ? xs[5] : -xs[5])
                + ((h & 4) ? xs[6] : -xs[6])
                - xs[7];
        const float t0 = 2.f * xs[0], t1 = 2.f * xs[1],
                    t2 = 2.f * xs[2], t3 = 2.f * xs[3];
        float* row = &lut[pos][h << 4];
        row[ 0] = e;                       // Gray walk of low nibble:
        e += t0; row[ 1] = e;              // 0,1,3,2,6,7,5,4,12,13,15,14,10,11,9,8
        e += t1; row[ 3] = e;
        e -= t0; row[ 2] = e;
        e += t2; row[ 6] = e;
        e += t0; row[ 7] = e;
        e -= t1; row[ 5] = e;
        e -= t0; row[ 4] = e;
        e += t3; row[12] = e;
        e += t0; row[13] = e;
        e += t1; row[15] = e;
        e -= t0; row[14] = e;
        e -= t2; row[10] = e;
        e += t0; row[11] = e;
        e -= t1; row[ 9] = e;
        e -= t0; row[ 8] = e;
    }
    __syncthreads();

    const int lane = tid & 63;
    const int wave = tid >> 6;        // 0..7
    const int sub  = lane & 15;       // which int4 within the 256B row-slice
    const int rsub = lane >> 4;       // row-within-4 for this wave-iteration
    const int rowBase = chunk * ROWS_PER_BLK + wave * (ROWS_PER_BLK / 8);
    const int pos0 = sub * 4;
    const int g    = s * 4 + (sub >> 2);   // global scale-group of this lane

    const intv4* __restrict__ p4 = (const intv4*)packed;

#pragma unroll 4
    for (int t = 0; t < 16; ++t) {
        const int r = rowBase + t * 4 + rsub;
        // 16 lanes cover one row's 256 B slice; 4 rows per wave-load (nt: stream-once)
        const intv4 v = __builtin_nontemporal_load(
            &p4[r * (KP / 4) + s * (SLICE_I / 4) + sub]);
        float acc = 0.f;
        const int bb[4] = { v.x & 255, v.y & 255, v.z & 255, v.w & 255 };
#pragma unroll
        for (int j = 0; j < 4; ++j) {
            const int b   = bb[j];
            const int m   = b >> 7;                    // 0 or 1
            const int idx = (b ^ (-m)) & 127;          // complement if bit7
            const float val = lut[pos0 + j][idx];
            acc += __int_as_float(__float_as_int(val) ^ (m << 31));
        }
        // butterfly over the 4 lanes covering one group (128 weights)
        acc += __shfl_xor(acc, 1);
        acc += __shfl_xor(acc, 2);
        if ((sub & 3) == 0)            // leaders: sub = 0,4,8,12 -> groups 4s..4s+3
            pTh[g * NROWS + r] = __float2half_rn(acc);   // NORMAL store (release-able)
    }

    // ---- ticket: release pTh, count this block's slice as done for `chunk`
    __threadfence();                               // device-scope release
    if (tid == 0) ticket = atomicAdd(&cnt[chunk], 1);
    __syncthreads();
    if (ticket != NSLICES - 1) return;             // not the last -> done
    __threadfence();                               // acquire others' pTh

    // ---- tail: scale-pass for this chunk's 512 rows (R4 pass2 x 8 sub-tiles).
    // Overlay scale tile + partials onto the dead LUT (16.6 KB + 2.3 KB < 33.8 KB).
    float* smemf = &lut[0][0];
    float (*s_s)[65]   = (float(*)[65])smemf;          // 64 x 65
    float (*s_part)[9] = (float(*)[9])(smemf + 64*65); // 64 x 9

    for (int st = 0; st < 8; ++st) {
        const int rb = chunk * ROWS_PER_BLK + st * 64;
        __syncthreads();   // previous sub-tile fully consumed (st=0: LUT dead)
        // stage 64 rows x 64 scales = 16 KB, fully coalesced float4 loads
        const float4* s4 = (const float4*)(scales + (size_t)rb * GROUPS);
#pragma unroll
        for (int i = 0; i < 2; ++i) {
            const int idx = i * 512 + tid;
            const float4 v = s4[idx];
            const int rr = idx >> 4;
            const int cc = (idx & 15) * 4;
            s_s[rr][cc + 0] = v.x;
            s_s[rr][cc + 1] = v.y;
            s_s[rr][cc + 2] = v.z;
            s_s[rr][cc + 3] = v.w;
        }
        __syncthreads();

        const int r = rb + lane;
        float acc = 0.f;
#pragma unroll
        for (int i = 0; i < 8; ++i) {
            const int gg = wave * 8 + i;
            acc += __half2float(pTh[(size_t)gg * NROWS + r]) * s_s[lane][gg];
        }
        s_part[lane][wave] = acc;
        __syncthreads();

        if (wave == 0) {
            float a = 0.f;
#pragma unroll
            for (int w = 0; w < 8; ++w) a += s_part[lane][w];
            out[r] = a;
        }
    }
}

// ---------------------------------------------------------------------------
// Fallback (proven Round-2 path) if ws can't hold pTh + counters.
// ---------------------------------------------------------------------------
__global__ __launch_bounds__(BLK, 4)
void bitlin_main_atomic(const float* __restrict__ x,
                        const int* __restrict__ packed,
                        const float* __restrict__ scales,
                        float* __restrict__ ws)
{
    __shared__ float lut[32][256];
    const int s     = blockIdx.x & 31;
    const int chunk = blockIdx.x >> 5;
    const int tid   = threadIdx.x;
    {
        const int pos = tid >> 4;
        const int b0  = (tid & 15) << 4;
        float xs[8];
#pragma unroll
        for (int i = 0; i < 8; ++i) xs[i] = x[s * 256 + pos * 8 + i];
#pragma unroll
        for (int b = 0; b < 16; ++b) {
            const int byte = b0 + b;
            float v = 0.f;
#pragma unroll
            for (int i = 0; i < 8; ++i)
                v += ((byte >> i) & 1) ? xs[i] : -xs[i];
            lut[pos][byte] = v;
        }
    }
    __syncthreads();

    const int lane = tid & 63;
    const int wave = tid >> 6;
    const int sub  = lane & 7;
    const int rsub = lane >> 3;
    const int rowBase = chunk * 512 + wave * 64;
    const int4* __restrict__ p4 = (const int4*)packed;

#pragma unroll
    for (int t = 0; t < 8; ++t) {
        const int r = rowBase + t * 8 + rsub;
        const int4 v = p4[r * (KP / 4) + s * 8 + sub];
        const float sc = scales[r * GROUPS + s * 2 + (sub >> 2)];
        const int pos0 = sub * 4;
        float acc = lut[pos0 + 0][v.x & 255]
                  + lut[pos0 + 1][v.y & 255]
                  + lut[pos0 + 2][v.z & 255]
                  + lut[pos0 + 3][v.w & 255];
        acc *= sc;
        acc += __shfl_xor(acc, 1);
        acc += __shfl_xor(acc, 2);
        acc += __shfl_xor(acc, 4);
        if (sub == 0) atomicAdd(&ws[r], acc);
    }
}

__global__ __launch_bounds__(512)
void bitlin_fin(const float* __restrict__ ws, float* __restrict__ out)
{
    const int i = blockIdx.x * blockDim.x + threadIdx.x;
    out[i] = ws[i];
}

extern "C" void kernel_launch(void* const* d_in, const int* in_sizes, int n_in,
                              void* d_out, int out_size, void* d_ws, size_t ws_size,
                              hipStream_t stream)
{
    const float* x      = (const float*)d_in[0];
    const int*   packed = (const int*)d_in[1];
    const float* scales = (const float*)d_in[2];

    const size_t pTh_bytes = (size_t)GROUPS * NROWS * sizeof(__half);  // 4.2 MB
    const size_t cnt_bytes = RCHUNKS * sizeof(int);                    // 256 B

    if (ws_size >= pTh_bytes + cnt_bytes) {
        __half* pTh = (__half*)d_ws;
        int*    cnt = (int*)((char*)d_ws + pTh_bytes);
        hipMemsetAsync(cnt, 0, cnt_bytes, stream);     // reset tickets each call
        bitlin_fused<<<dim3(NSLICES * RCHUNKS), dim3(BLK), 0, stream>>>(
            x, packed, scales, pTh, cnt, (float*)d_out);
    } else {
        // fallback: proven Round-2 fused path
        float* ws = (float*)d_ws;
        hipMemsetAsync(ws, 0, NROWS * sizeof(float), stream);
        bitlin_main_atomic<<<dim3(32 * (NROWS / 512)), dim3(BLK), 0, stream>>>(x, packed, scales, ws);
        bitlin_fin<<<dim3(NROWS / 512), dim3(512), 0, stream>>>(ws, (float*)d_out);
    }
}

// Round 14
// 114.324 us; speedup vs baseline: 2.8784x; 2.8784x over previous
//
#include <hip/hip_runtime.h>
#include <hip/hip_fp16.h>

// Problem geometry (fixed by the reference)
#define NROWS   32768      // out_features N
#define KTOT    8192       // in_features K
#define KP      1024       // packed bytes per row (each stored as one int32 on device)
#define GROUPS  64         // scale groups per row (K/128)

// Split-K design (R7, proven): 512-weight slices + sign-symmetric 128-entry LUT
#define SLICE_W 512        // weights per K-slice
#define SLICE_I 64         // int32 elements per slice per row (256 B granule)
#define NSLICES (KTOT / SLICE_W)        // 16
#define BLK     512        // 8 waves
#define ROWS_PER_BLK 512
#define RCHUNKS (NROWS / ROWS_PER_BLK)  // 64 -> grid 1024 = 4 blocks/CU
#define LUTW    132        // 128 entries + 4 pad

// ---------------------------------------------------------------------------
// Pass 1 + ticket-fused scale pass.
// Main phase: R7 verbatim (plain loads; nt loads = 10x latency disaster R12,
// nt stores break release ordering R11).
// Ticket (fixed in R14): pTh stores -> __syncthreads() [drains ALL threads'
// vmcnt before the barrier] -> tid0: __threadfence() release + device-scope
// atomicAdd -> __syncthreads() broadcast. R13's bug: the fence was issued
// per-thread BEFORE the barrier, so tid0's atomic could land while other
// threads' stores were still in flight -> flaky stale reads in the tail.
// Tail phase: 16th block per chunk acquires (__threadfence) and runs the
// proven R4 scale-pass; scales staged into LDS overlaid on the dead LUT.
// ---------------------------------------------------------------------------
__global__ __launch_bounds__(BLK, 8)
void bitlin_fused(const float* __restrict__ x,
                  const int* __restrict__ packed,
                  const float* __restrict__ scales,
                  __half* __restrict__ pTh,
                  int* __restrict__ cnt,
                  float* __restrict__ out)
{
    __shared__ float lut[SLICE_W / 8][LUTW];   // 33.8 KB; overlaid in tail
    __shared__ int ticket;

    const int s     = blockIdx.x & (NSLICES - 1);  // K-slice id (0..15)
    const int chunk = blockIdx.x >> 4;             // row-chunk id (0..63)
    const int tid   = threadIdx.x;

    // ---- Build half-LUT (R7 verbatim): thread owns (pos = tid>>3, h = tid&7),
    // Gray-walks the low nibble. idx bits 0..3 -> x0..x3, 4..6 -> x4..x6;
    // bit7 == 0 => x7 coefficient always -1.
    {
        const int pos = tid >> 3;          // 0..63
        const int h   = tid & 7;
        float xs[8];
#pragma unroll
        for (int i = 0; i < 8; ++i) xs[i] = x[s * SLICE_W + pos * 8 + i];
        float e = -xs[0] - xs[1] - xs[2] - xs[3]
                + ((h & 1) ? xs[4] : -xs[4])
                + ((h & 2) ? xs[5] : -xs[5])
                + ((h & 4) ? xs[6] : -xs[6])
                - xs[7];
        const float t0 = 2.f * xs[0], t1 = 2.f * xs[1],
                    t2 = 2.f * xs[2], t3 = 2.f * xs[3];
        float* row = &lut[pos][h << 4];
        row[ 0] = e;                       // Gray walk of low nibble:
        e += t0; row[ 1] = e;              // 0,1,3,2,6,7,5,4,12,13,15,14,10,11,9,8
        e += t1; row[ 3] = e;
        e -= t0; row[ 2] = e;
        e += t2; row[ 6] = e;
        e += t0; row[ 7] = e;
        e -= t1; row[ 5] = e;
        e -= t0; row[ 4] = e;
        e += t3; row[12] = e;
        e += t0; row[13] = e;
        e += t1; row[15] = e;
        e -= t0; row[14] = e;
        e -= t2; row[10] = e;
        e += t0; row[11] = e;
        e -= t1; row[ 9] = e;
        e -= t0; row[ 8] = e;
    }
    __syncthreads();

    const int lane = tid & 63;
    const int wave = tid >> 6;        // 0..7
    const int sub  = lane & 15;       // which int4 within the 256B row-slice
    const int rsub = lane >> 4;       // row-within-4 for this wave-iteration
    const int rowBase = chunk * ROWS_PER_BLK + wave * (ROWS_PER_BLK / 8);
    const int pos0 = sub * 4;
    const int g    = s * 4 + (sub >> 2);   // global scale-group of this lane

    const int4* __restrict__ p4 = (const int4*)packed;

#pragma unroll 4
    for (int t = 0; t < 16; ++t) {
        const int r = rowBase + t * 4 + rsub;
        // 16 lanes cover one row's 256 B slice; 4 rows per wave-load
        const int4 v = p4[r * (KP / 4) + s * (SLICE_I / 4) + sub];
        float acc = 0.f;
        const int bb[4] = { v.x & 255, v.y & 255, v.z & 255, v.w & 255 };
#pragma unroll
        for (int j = 0; j < 4; ++j) {
            const int b   = bb[j];
            const int m   = b >> 7;                    // 0 or 1
            const int idx = (b ^ (-m)) & 127;          // complement if bit7
            const float val = lut[pos0 + j][idx];
            acc += __int_as_float(__float_as_int(val) ^ (m << 31));
        }
        // butterfly over the 4 lanes covering one group (128 weights)
        acc += __shfl_xor(acc, 1);
        acc += __shfl_xor(acc, 2);
        if ((sub & 3) == 0)            // leaders: sub = 0,4,8,12 -> groups 4s..4s+3
            pTh[g * NROWS + r] = __float2half_rn(acc);
    }

    // ---- ticket (R14-fixed ordering):
    __syncthreads();                   // drain ALL threads' pTh stores (vmcnt 0
                                       // enforced per-thread before s_barrier)
    if (tid == 0) {
        __threadfence();               // agent-scope release of the block's stores
        ticket = atomicAdd(&cnt[chunk], 1);
    }
    __syncthreads();                   // broadcast ticket
    if (ticket != NSLICES - 1) return; // not the last block of this chunk -> done
    __threadfence();                   // acquire: invalidate caches, see others' pTh

    // ---- tail: scale-pass for this chunk's 512 rows (R4 pass2 x 8 sub-tiles).
    // Overlay scale tile + partials onto the dead LUT (16.6 KB + 2.3 KB < 33.8 KB).
    float* smemf = &lut[0][0];
    float (*s_s)[65]   = (float(*)[65])smemf;          // 64 x 65
    float (*s_part)[9] = (float(*)[9])(smemf + 64*65); // 64 x 9

    for (int st = 0; st < 8; ++st) {
        const int rb = chunk * ROWS_PER_BLK + st * 64;
        __syncthreads();   // previous sub-tile fully consumed (st=0: LUT dead)
        // stage 64 rows x 64 scales = 16 KB, fully coalesced float4 loads
        const float4* s4 = (const float4*)(scales + (size_t)rb * GROUPS);
#pragma unroll
        for (int i = 0; i < 2; ++i) {
            const int idx = i * 512 + tid;
            const float4 v = s4[idx];
            const int rr = idx >> 4;
            const int cc = (idx & 15) * 4;
            s_s[rr][cc + 0] = v.x;
            s_s[rr][cc + 1] = v.y;
            s_s[rr][cc + 2] = v.z;
            s_s[rr][cc + 3] = v.w;
        }
        __syncthreads();

        const int r = rb + lane;
        float acc = 0.f;
#pragma unroll
        for (int i = 0; i < 8; ++i) {
            const int gg = wave * 8 + i;
            acc += __half2float(pTh[(size_t)gg * NROWS + r]) * s_s[lane][gg];
        }
        s_part[lane][wave] = acc;
        __syncthreads();

        if (wave == 0) {
            float a = 0.f;
#pragma unroll
            for (int w = 0; w < 8; ++w) a += s_part[lane][w];
            out[r] = a;
        }
    }
}

// ---------------------------------------------------------------------------
// Fallback (proven Round-2 path) if ws can't hold pTh + counters.
// ---------------------------------------------------------------------------
__global__ __launch_bounds__(BLK, 4)
void bitlin_main_atomic(const float* __restrict__ x,
                        const int* __restrict__ packed,
                        const float* __restrict__ scales,
                        float* __restrict__ ws)
{
    __shared__ float lut[32][256];
    const int s     = blockIdx.x & 31;
    const int chunk = blockIdx.x >> 5;
    const int tid   = threadIdx.x;
    {
        const int pos = tid >> 4;
        const int b0  = (tid & 15) << 4;
        float xs[8];
#pragma unroll
        for (int i = 0; i < 8; ++i) xs[i] = x[s * 256 + pos * 8 + i];
#pragma unroll
        for (int b = 0; b < 16; ++b) {
            const int byte = b0 + b;
            float v = 0.f;
#pragma unroll
            for (int i = 0; i < 8; ++i)
                v += ((byte >> i) & 1) ? xs[i] : -xs[i];
            lut[pos][byte] = v;
        }
    }
    __syncthreads();

    const int lane = tid & 63;
    const int wave = tid >> 6;
    const int sub  = lane & 7;
    const int rsub = lane >> 3;
    const int rowBase = chunk * 512 + wave * 64;
    const int4* __restrict__ p4 = (const int4*)packed;

#pragma unroll
    for (int t = 0; t < 8; ++t) {
        const int r = rowBase + t * 8 + rsub;
        const int4 v = p4[r * (KP / 4) + s * 8 + sub];
        const float sc = scales[r * GROUPS + s * 2 + (sub >> 2)];
        const int pos0 = sub * 4;
        float acc = lut[pos0 + 0][v.x & 255]
                  + lut[pos0 + 1][v.y & 255]
                  + lut[pos0 + 2][v.z & 255]
                  + lut[pos0 + 3][v.w & 255];
        acc *= sc;
        acc += __shfl_xor(acc, 1);
        acc += __shfl_xor(acc, 2);
        acc += __shfl_xor(acc, 4);
        if (sub == 0) atomicAdd(&ws[r], acc);
    }
}

__global__ __launch_bounds__(512)
void bitlin_fin(const float* __restrict__ ws, float* __restrict__ out)
{
    const int i = blockIdx.x * blockDim.x + threadIdx.x;
    out[i] = ws[i];
}

extern "C" void kernel_launch(void* const* d_in, const int* in_sizes, int n_in,
                              void* d_out, int out_size, void* d_ws, size_t ws_size,
                              hipStream_t stream)
{
    const float* x      = (const float*)d_in[0];
    const int*   packed = (const int*)d_in[1];
    const float* scales = (const float*)d_in[2];

    const size_t pTh_bytes = (size_t)GROUPS * NROWS * sizeof(__half);  // 4.2 MB
    const size_t cnt_bytes = RCHUNKS * sizeof(int);                    // 256 B

    if (ws_size >= pTh_bytes + cnt_bytes) {
        __half* pTh = (__half*)d_ws;
        int*    cnt = (int*)((char*)d_ws + pTh_bytes);
        hipMemsetAsync(cnt, 0, cnt_bytes, stream);     // reset tickets each call
        bitlin_fused<<<dim3(NSLICES * RCHUNKS), dim3(BLK), 0, stream>>>(
            x, packed, scales, pTh, cnt, (float*)d_out);
    } else {
        // fallback: proven Round-2 fused path
        float* ws = (float*)d_ws;
        hipMemsetAsync(ws, 0, NROWS * sizeof(float), stream);
        bitlin_main_atomic<<<dim3(32 * (NROWS / 512)), dim3(BLK), 0, stream>>>(x, packed, scales, ws);
        bitlin_fin<<<dim3(NROWS / 512), dim3(512), 0, stream>>>(ws, (float*)d_out);
    }
}

// Round 15
// 30.539 us; speedup vs baseline: 10.7754x; 3.7435x over previous
//
#include <hip/hip_runtime.h>
#include <hip/hip_fp16.h>

// Problem geometry (fixed by the reference)
#define NROWS   32768      // out_features N
#define KTOT    8192       // in_features K
#define KP      1024       // packed bytes per row (each stored as one int32 on device)
#define GROUPS  64         // scale groups per row (K/128)

// Split-K design (R7, proven): 512-weight slices + sign-symmetric 128-entry LUT
#define SLICE_W 512        // weights per K-slice
#define SLICE_I 64         // int32 elements per slice per row (256 B granule)
#define NSLICES (KTOT / SLICE_W)        // 16
#define BLK     512        // 8 waves
#define ROWS_PER_BLK 512
#define RCHUNKS (NROWS / ROWS_PER_BLK)  // 64 -> grid 1024 = 4 blocks/CU
#define LUTW    132        // 128 entries + 4 pad

// ---------------------------------------------------------------------------
// Pass 1 (R7 + explicit 8-deep load pipeline): per-(row, group) UNSCALED
// partials -> pTh[g*NROWS + r] (__half). One block = one K-slice x 512 rows.
// Two-kernel structure is final: ticket fusion disproven (R11/R12/R14 —
// per-block device-scope __threadfence = L2 writeback storm, 4-10x slower).
// nt loads/stores banned (R12: latency catastrophe / R11: fence-breaking).
// ---------------------------------------------------------------------------
__global__ __launch_bounds__(BLK, 8)
void bitlin_partials(const float* __restrict__ x,
                     const int* __restrict__ packed,
                     __half* __restrict__ pTh)
{
    __shared__ float lut[SLICE_W / 8][LUTW];   // 33.8 KB

    const int s     = blockIdx.x & (NSLICES - 1);  // K-slice id (0..15)
    const int chunk = blockIdx.x >> 4;             // row-chunk id (0..63)
    const int tid   = threadIdx.x;

    // ---- Build half-LUT (R7 verbatim): thread owns (pos = tid>>3, h = tid&7),
    // Gray-walks the low nibble. idx bits 0..3 -> x0..x3, 4..6 -> x4..x6;
    // bit7 == 0 => x7 coefficient always -1 (sign symmetry: dot(b)=-dot(b^0xFF)).
    {
        const int pos = tid >> 3;          // 0..63
        const int h   = tid & 7;
        float xs[8];
#pragma unroll
        for (int i = 0; i < 8; ++i) xs[i] = x[s * SLICE_W + pos * 8 + i];
        float e = -xs[0] - xs[1] - xs[2] - xs[3]
                + ((h & 1) ? xs[4] : -xs[4])
                + ((h & 2) ? xs[5] : -xs[5])
                + ((h & 4) ? xs[6] : -xs[6])
                - xs[7];
        const float t0 = 2.f * xs[0], t1 = 2.f * xs[1],
                    t2 = 2.f * xs[2], t3 = 2.f * xs[3];
        float* row = &lut[pos][h << 4];
        row[ 0] = e;                       // Gray walk of low nibble:
        e += t0; row[ 1] = e;              // 0,1,3,2,6,7,5,4,12,13,15,14,10,11,9,8
        e += t1; row[ 3] = e;
        e -= t0; row[ 2] = e;
        e += t2; row[ 6] = e;
        e += t0; row[ 7] = e;
        e -= t1; row[ 5] = e;
        e -= t0; row[ 4] = e;
        e += t3; row[12] = e;
        e += t0; row[13] = e;
        e += t1; row[15] = e;
        e -= t0; row[14] = e;
        e -= t2; row[10] = e;
        e += t0; row[11] = e;
        e -= t1; row[ 9] = e;
        e -= t0; row[ 8] = e;
    }
    __syncthreads();

    const int lane = tid & 63;
    const int wave = tid >> 6;        // 0..7
    const int sub  = lane & 15;       // which int4 within the 256B row-slice
    const int rsub = lane >> 4;       // row-within-4 for this wave-iteration
    const int rowBase = chunk * ROWS_PER_BLK + wave * (ROWS_PER_BLK / 8);
    const int pos0 = sub * 4;
    const int g    = s * 4 + (sub >> 2);   // global scale-group of this lane

    const int4* __restrict__ p4 = (const int4*)packed;
    // per-lane base: row (rowBase+rsub), this slice, this int4
    const int4* __restrict__ base =
        &p4[(size_t)(rowBase + rsub) * (KP / 4) + s * (SLICE_I / 4) + sub];
    // row stride = KP/4 int4; iteration t advances 4 rows = 1024 int4

#define LOADQ(v0, v1, v2, v3, tb)                \
    v0 = base[((tb) + 0) * 4 * (KP / 4)];        \
    v1 = base[((tb) + 1) * 4 * (KP / 4)];        \
    v2 = base[((tb) + 2) * 4 * (KP / 4)];        \
    v3 = base[((tb) + 3) * 4 * (KP / 4)];

#define CONSQ(v0, v1, v2, v3, tb) {                                        \
    const int4 vv[4] = { v0, v1, v2, v3 };                                 \
    _Pragma("unroll")                                                      \
    for (int q = 0; q < 4; ++q) {                                          \
        const int r = rowBase + ((tb) + q) * 4 + rsub;                     \
        const int bb[4] = { vv[q].x & 255, vv[q].y & 255,                  \
                            vv[q].z & 255, vv[q].w & 255 };                \
        float acc = 0.f;                                                   \
        _Pragma("unroll")                                                  \
        for (int j = 0; j < 4; ++j) {                                      \
            const int b   = bb[j];                                         \
            const int m   = b >> 7;                                        \
            const int idx = (b ^ (-m)) & 127;                              \
            const float val = lut[pos0 + j][idx];                          \
            acc += __int_as_float(__float_as_int(val) ^ (m << 31));        \
        }                                                                  \
        acc += __shfl_xor(acc, 1);                                         \
        acc += __shfl_xor(acc, 2);                                         \
        if ((sub & 3) == 0)                                                \
            pTh[g * NROWS + r] = __float2half_rn(acc);                     \
    } }

    // ---- software pipeline: 8 int4 in flight (batch k+1 loads overlap
    // batch k's LDS lookups) — raises per-wave MLP from 4 to 8 loads.
    int4 A0, A1, A2, A3, B0, B1, B2, B3;
    LOADQ(A0, A1, A2, A3, 0)
    LOADQ(B0, B1, B2, B3, 4)
    CONSQ(A0, A1, A2, A3, 0)
    LOADQ(A0, A1, A2, A3, 8)
    CONSQ(B0, B1, B2, B3, 4)
    LOADQ(B0, B1, B2, B3, 12)
    CONSQ(A0, A1, A2, A3, 8)
    CONSQ(B0, B1, B2, B3, 12)
#undef LOADQ
#undef CONSQ
}

// ---------------------------------------------------------------------------
// Pass 2 (proven R4/R7 kernel, verbatim): out[r] = sum_g pTh[g*N+r]*sc[r][g]
// Block = 512 threads x 64 rows; coalesced reads; scales staged in padded LDS.
// ---------------------------------------------------------------------------
__global__ __launch_bounds__(512)
void bitlin_scale(const __half* __restrict__ pTh,
                  const float* __restrict__ scales,
                  float* __restrict__ out)
{
    __shared__ float s_s[64][65];    // padded: conflict-free column reads
    __shared__ float s_part[64][9];  // per-(row, wave) partials, padded

    const int tid     = threadIdx.x;
    const int lane    = tid & 63;
    const int wave    = tid >> 6;
    const int rowBase = blockIdx.x * 64;

    const float4* s4 = (const float4*)(scales + (size_t)rowBase * GROUPS);
#pragma unroll
    for (int i = 0; i < 2; ++i) {
        const int idx = i * 512 + tid;
        const float4 v = s4[idx];
        const int r = idx >> 4;
        const int c = (idx & 15) * 4;
        s_s[r][c + 0] = v.x;
        s_s[r][c + 1] = v.y;
        s_s[r][c + 2] = v.z;
        s_s[r][c + 3] = v.w;
    }
    __syncthreads();

    const int r = rowBase + lane;
    float acc = 0.f;
#pragma unroll
    for (int i = 0; i < 8; ++i) {
        const int g = wave * 8 + i;
        acc += __half2float(pTh[(size_t)g * NROWS + r]) * s_s[lane][g];
    }
    s_part[lane][wave] = acc;
    __syncthreads();

    if (wave == 0) {
        float a = 0.f;
#pragma unroll
        for (int w = 0; w < 8; ++w) a += s_part[lane][w];
        out[r] = a;
    }
}

// ---------------------------------------------------------------------------
// Fallback (proven Round-2 path) if ws can't hold the 4.2 MB partial matrix.
// ---------------------------------------------------------------------------
__global__ __launch_bounds__(BLK, 4)
void bitlin_main_atomic(const float* __restrict__ x,
                        const int* __restrict__ packed,
                        const float* __restrict__ scales,
                        float* __restrict__ ws)
{
    __shared__ float lut[32][256];
    const int s     = blockIdx.x & 31;
    const int chunk = blockIdx.x >> 5;
    const int tid   = threadIdx.x;
    {
        const int pos = tid >> 4;
        const int b0  = (tid & 15) << 4;
        float xs[8];
#pragma unroll
        for (int i = 0; i < 8; ++i) xs[i] = x[s * 256 + pos * 8 + i];
#pragma unroll
        for (int b = 0; b < 16; ++b) {
            const int byte = b0 + b;
            float v = 0.f;
#pragma unroll
            for (int i = 0; i < 8; ++i)
                v += ((byte >> i) & 1) ? xs[i] : -xs[i];
            lut[pos][byte] = v;
        }
    }
    __syncthreads();

    const int lane = tid & 63;
    const int wave = tid >> 6;
    const int sub  = lane & 7;
    const int rsub = lane >> 3;
    const int rowBase = chunk * 512 + wave * 64;
    const int4* __restrict__ p4 = (const int4*)packed;

#pragma unroll
    for (int t = 0; t < 8; ++t) {
        const int r = rowBase + t * 8 + rsub;
        const int4 v = p4[r * (KP / 4) + s * 8 + sub];
        const float sc = scales[r * GROUPS + s * 2 + (sub >> 2)];
        const int pos0 = sub * 4;
        float acc = lut[pos0 + 0][v.x & 255]
                  + lut[pos0 + 1][v.y & 255]
                  + lut[pos0 + 2][v.z & 255]
                  + lut[pos0 + 3][v.w & 255];
        acc *= sc;
        acc += __shfl_xor(acc, 1);
        acc += __shfl_xor(acc, 2);
        acc += __shfl_xor(acc, 4);
        if (sub == 0) atomicAdd(&ws[r], acc);
    }
}

__global__ __launch_bounds__(512)
void bitlin_fin(const float* __restrict__ ws, float* __restrict__ out)
{
    const int i = blockIdx.x * blockDim.x + threadIdx.x;
    out[i] = ws[i];
}

extern "C" void kernel_launch(void* const* d_in, const int* in_sizes, int n_in,
                              void* d_out, int out_size, void* d_ws, size_t ws_size,
                              hipStream_t stream)
{
    const float* x      = (const float*)d_in[0];
    const int*   packed = (const int*)d_in[1];
    const float* scales = (const float*)d_in[2];

    const size_t pTh_bytes = (size_t)GROUPS * NROWS * sizeof(__half);  // 4.2 MB

    if (ws_size >= pTh_bytes) {
        __half* pTh = (__half*)d_ws;
        bitlin_partials<<<dim3(NSLICES * RCHUNKS), dim3(BLK), 0, stream>>>(x, packed, pTh);
        bitlin_scale<<<dim3(NROWS / 64), dim3(512), 0, stream>>>(pTh, scales, (float*)d_out);
    } else {
        // fallback: proven Round-2 fused path
        float* ws = (float*)d_ws;
        hipMemsetAsync(ws, 0, NROWS * sizeof(float), stream);
        bitlin_main_atomic<<<dim3(32 * (NROWS / 512)), dim3(BLK), 0, stream>>>(x, packed, scales, ws);
        bitlin_fin<<<dim3(NROWS / 512), dim3(512), 0, stream>>>(ws, (float*)d_out);
    }
}